// Round 7
// baseline (13068.011 us; speedup 1.0000x reference)
//
#include <hip/hip_runtime.h>

// RNNModel: 2-layer LSTM (B=64,T=400,E=H=500) + MLP head (800->100->2).
// Round 7: r6's one-dispatch-per-grid-step structure (401 step dispatches,
// L0 computes t=s, L1 computes t=s-1; kernel boundaries = grid barrier)
// with r1's direct-from-L2 weight K-loop (no weight LDS, no global_load_lds,
// 2 syncthreads/step). XCD-grouped block map keeps each XCD's 2MB weight
// slice L2-resident (proven in r4: FETCH 0.38GB total).
// Numerics: f32 125-term serial chunks, f64 combine over 8 chunks, f64
// gates/cell (c in ws as f64), f32 h, f64 head — absmax 0.0 family.

#define NTHR 512
#define Bn 64
#define Tn 400
#define Hn 500

#define OFF_H1 0            // float [2][64*500] h1 (row-major [b][u])
#define OFF_H2 512000       // float [2][64*500] h2
#define OFF_C1 1024000      // double [64*500] c1
#define OFF_C2 1280000      // double [64*500] c2
#define OFF_D1 1536000      // float [64*800]
#define OFF_D2 1740800      // float [64*100]
#define WS_ZERO 1536000     // zero h+c only; d1/d2 fully overwritten

extern "C" __global__ void __launch_bounds__(NTHR)
rnn_step(const int* __restrict__ X, const float* __restrict__ embed,
         const float* __restrict__ k1, const float* __restrict__ b1g,
         const float* __restrict__ k2, const float* __restrict__ b2g,
         char* __restrict__ ws, int s)
{
    __shared__ float s_x[16 * 1020];   // 16 batch rows x 1000 (stride 1020)
    __shared__ float s_comb[8192];     // [kh8][g4][256] chunk partials

    float* h1b = (float*)(ws + OFF_H1);
    float* h2b = (float*)(ws + OFF_H2);

    const int bid = blockIdx.x;
    const int tid = threadIdx.x;
    // XCD-grouped duplicates: 4 batch-tiles of a slice share bid&7
    const int rr_ = bid >> 3;
    const int slice = (bid & 7) * 8 + (rr_ >> 2);  // 0..63
    const int btile = rr_ & 3;
    const int L = slice >> 5;
    const int ut = slice & 31;          // unit tile: units ut*16..+15
    const int b0 = btile * 16;

    const bool active = L ? (s >= 1) : (s < Tn);
    if (!active) return;

    const float* Wm = L ? k2 : k1;      // [1000][2000], gates i,j,f,o
    const float* bv = L ? b2g : b1g;
    double* cb = (double*)(ws + (L ? OFF_C2 : OFF_C1));

    const int ug = tid & 3;             // col quad within 16-unit tile
    const int bl = (tid >> 2) & 15;     // batch lane within tile
    const int kh = tid >> 6;            // K chunk 0..7 (125 each)
    const int ugc = min(ut * 4 + ug, 124);  // clamped global col-quad

    const int cur = s & 1, prv = cur ^ 1;
    const float* h1p = h1b + prv * 32000;
    const float* h2p = h2b + prv * 32000;
    float* hout = (L ? h2b : h1b) + cur * 32000;
    const int t = L ? (s - 1) : s;

    // ---------- stage x rows [16][1000] (row-major, stride 1020) ----------
    {
        const int bi = tid & 15;
        const int q0 = tid >> 4;        // 0..31
        const float* rowA;
        const float* rowB;
        if (L == 0) {
            rowA = embed + (size_t)X[(b0 + bi) * Tn + t] * 500;
            rowB = h1p + (b0 + bi) * 500;
        } else {
            rowA = h1p + (b0 + bi) * 500;
            rowB = h2p + (b0 + bi) * 500;
        }
        #pragma unroll
        for (int j = 0; j < 8; ++j) {
            const int q = q0 + 32 * j;
            if (q < 250) {
                const int k = 4 * q;
                const float4 v = (k < 500) ? *(const float4*)(rowA + k)
                                           : *(const float4*)(rowB + (k - 500));
                *(float4*)&s_x[bi * 1020 + k] = v;
            }
        }
    }
    __syncthreads();

    // ---------- K-loop: 125 iters, weights straight from L2 ----------
    const float* wp0 = Wm + (size_t)(kh * 125) * 2000 + ugc * 4;
    const float* inp = s_x + bl * 1020 + kh * 125;
    float4 a0 = {0.f, 0.f, 0.f, 0.f};
    float4 a1 = a0, a2 = a0, a3 = a0;
    #pragma unroll 5
    for (int i = 0; i < 125; ++i) {
        const float x = inp[i];
        const float4 w0 = *(const float4*)(wp0);
        const float4 w1v = *(const float4*)(wp0 + 500);
        const float4 w2v = *(const float4*)(wp0 + 1000);
        const float4 w3v = *(const float4*)(wp0 + 1500);
        a0.x = fmaf(x, w0.x, a0.x);
        a0.y = fmaf(x, w0.y, a0.y);
        a0.z = fmaf(x, w0.z, a0.z);
        a0.w = fmaf(x, w0.w, a0.w);
        a1.x = fmaf(x, w1v.x, a1.x);
        a1.y = fmaf(x, w1v.y, a1.y);
        a1.z = fmaf(x, w1v.z, a1.z);
        a1.w = fmaf(x, w1v.w, a1.w);
        a2.x = fmaf(x, w2v.x, a2.x);
        a2.y = fmaf(x, w2v.y, a2.y);
        a2.z = fmaf(x, w2v.z, a2.z);
        a2.w = fmaf(x, w2v.w, a2.w);
        a3.x = fmaf(x, w3v.x, a3.x);
        a3.y = fmaf(x, w3v.y, a3.y);
        a3.z = fmaf(x, w3v.z, a3.z);
        a3.w = fmaf(x, w3v.w, a3.w);
        wp0 += 2000;
    }
    // ---------- write chunk partials ----------
    {
        const int cbase = kh * 1024 + bl * 16 + ug * 4;
        *(float4*)&s_comb[cbase] = a0;
        *(float4*)&s_comb[cbase + 256] = a1;
        *(float4*)&s_comb[cbase + 512] = a2;
        *(float4*)&s_comb[cbase + 768] = a3;
    }
    __syncthreads();
    // ---------- gates: f64 combine over 8 chunks + LSTM cell ----------
    if (tid < 256) {
        const int uu = tid & 15;
        const int u = ut * 16 + uu;
        if (u < Hn) {
            const int b = b0 + (tid >> 4);
            double z0 = 0, z1 = 0, z2 = 0, z3 = 0;
            #pragma unroll
            for (int q = 0; q < 8; ++q) {
                z0 += (double)s_comb[q * 1024 + tid];
                z1 += (double)s_comb[q * 1024 + 256 + tid];
                z2 += (double)s_comb[q * 1024 + 512 + tid];
                z3 += (double)s_comb[q * 1024 + 768 + tid];
            }
            z0 += (double)bv[u];
            z1 += (double)bv[500 + u];
            z2 += (double)bv[1000 + u];
            z3 += (double)bv[1500 + u];
            const double gi = 1.0 / (1.0 + exp(-z0));
            const double gf = 1.0 / (1.0 + exp(-(z2 + 1.0)));
            const double go_ = 1.0 / (1.0 + exp(-z3));
            double* cc = cb + b * 500 + u;
            const double cnew = gf * (*cc) + gi * tanh(z1);
            *cc = cnew;
            hout[b * 500 + u] = (float)(go_ * tanh(cnew));
        }
    }
}

// ---------- dense head (f64 accumulation), round-1-validated math ----------
extern "C" __global__ void __launch_bounds__(256)
head1(const char* __restrict__ ws_c, const float* __restrict__ w1,
      const float* __restrict__ bw1, char* __restrict__ ws)
{
    const float* last = (const float*)(ws_c + OFF_H2);  // h2 phase 0 (t=399)
    float* d1p = (float*)(ws + OFF_D1);
    const int o = blockIdx.x * 256 + threadIdx.x;       // 200 blocks
    if (o >= 51200) return;
    const int b = o / 800, j = o - b * 800;
    const float* lr = last + b * 500;
    double acc = 0;
    for (int kk = 0; kk < 500; ++kk)
        acc += (double)lr[kk] * (double)w1[(size_t)kk * 800 + j];
    acc += (double)bw1[j];
    d1p[b * 800 + j] = (float)fmax(acc, 0.0);
}

extern "C" __global__ void __launch_bounds__(256)
head2(const char* __restrict__ ws_c, const float* __restrict__ w2,
      const float* __restrict__ bw2, char* __restrict__ ws)
{
    const float* d1p = (const float*)(ws_c + OFF_D1);
    float* d2p = (float*)(ws + OFF_D2);
    const int o = blockIdx.x * 256 + threadIdx.x;       // 25 blocks
    if (o >= 6400) return;
    const int b = o / 100, j = o - b * 100;
    const float* dr = d1p + b * 800;
    double acc = 0;
    for (int kk = 0; kk < 800; ++kk)
        acc += (double)dr[kk] * (double)w2[(size_t)kk * 100 + j];
    acc += (double)bw2[j];
    d2p[b * 100 + j] = (float)fmax(acc, 0.0);
}

extern "C" __global__ void __launch_bounds__(128)
head3(const char* __restrict__ ws_c, const float* __restrict__ wpm,
      const float* __restrict__ bpv, float* __restrict__ out)
{
    const float* d2p = (const float*)(ws_c + OFF_D2);
    const int tid = threadIdx.x;                        // 1 block, 128 thr
    const int b = tid >> 1, cc = tid & 1;
    const float* dr = d2p + b * 100;
    double acc = 0;
    for (int kk = 0; kk < 100; ++kk)
        acc += (double)dr[kk] * (double)wpm[kk * 2 + cc];
    acc += (double)bpv[cc];
    out[b * 2 + cc] = (float)acc;
}

extern "C" void kernel_launch(void* const* d_in, const int* in_sizes, int n_in,
                              void* d_out, int out_size, void* d_ws, size_t ws_size,
                              hipStream_t stream) {
    const int* X = (const int*)d_in[0];
    const float* embed = (const float*)d_in[1];
    const float* k1 = (const float*)d_in[2];
    const float* b1 = (const float*)d_in[3];
    const float* k2 = (const float*)d_in[4];
    const float* b2 = (const float*)d_in[5];
    const float* w1 = (const float*)d_in[6];
    const float* bw1 = (const float*)d_in[7];
    const float* w2 = (const float*)d_in[8];
    const float* bw2 = (const float*)d_in[9];
    const float* wpm = (const float*)d_in[10];
    const float* bpv = (const float*)d_in[11];
    char* ws = (char*)d_ws;

    // zero h (both phases) + c (f64) — captured: clean state every replay
    hipMemsetAsync(d_ws, 0, WS_ZERO, stream);

    for (int s = 0; s <= Tn; ++s)
        rnn_step<<<256, NTHR, 0, stream>>>(X, embed, k1, b1, k2, b2, ws, s);

    head1<<<200, 256, 0, stream>>>(ws, w1, bw1, ws);
    head2<<<25, 256, 0, stream>>>(ws, w2, bw2, ws);
    head3<<<1, 128, 0, stream>>>(ws, wpm, bpv, (float*)d_out);
}

// Round 8
// 5837.449 us; speedup vs baseline: 2.2387x; 2.2387x over previous
//
#include <hip/hip_runtime.h>

// RNNModel: 2-layer LSTM (B=64,T=400,E=H=500) + MLP head (800->100->2).
// Round 8: dispatch-per-step (r6 structure) + fully wave-local body:
//  - K padded to 1024 rows: [0,500)=x-part, [512,1012)=h-part (weight rows
//    shifted by -12), rows 500-511 & 1012-1023 zero (x=0 => any weight ok).
//  - wave w owns rows {128c+16w..+15} of every chunk c for BOTH weights and x
//    -> no cross-wave deps; chunk dbuf advanced with counted vmcnt(4), and
//    only ONE __syncthreads per step (before the gate combine).
//  - thread tile 8 cols x 8 batches, ks=lane&3 K-sublanes: 4 ds_read_b128
//    per 64 FMA; ks-combine via DPP quad-perm butterfly (pure VALU).
//  - weight LDS XOR-swizzled by row (applied to gll SOURCE col; dest linear).
//  - numerics: f32 serial 32-term, f32 quad tree, f64 combine over 8 waves,
//    f64 gates/cell (c in ws), f32 h, f64 head (absmax-0.0 family).

#define NTHR 512
#define Tn 400
#define Hn 500

#define OFF_H1 0            // float [2][500*64] transposed h1
#define OFF_H2 256000       // float [2][500*64] transposed h2
#define OFF_C1 512000       // double [500*64] c1 (index u*64+b)
#define OFF_C2 768000       // double [500*64] c2
#define OFF_D1 1024000      // float [64*800]
#define OFF_D2 1228800      // float [64*100]
#define WS_ZERO 1024000     // zero h+c; d1/d2 fully overwritten

__device__ __forceinline__ float qreduce(float v) {
    // butterfly over lanes ^1 and ^2 (quad_perm DPP, pure VALU pipe)
    int t = __builtin_amdgcn_update_dpp(0, __float_as_int(v), 0xB1, 0xF, 0xF, true);
    v += __int_as_float(t);
    t = __builtin_amdgcn_update_dpp(0, __float_as_int(v), 0x4E, 0xF, 0xF, true);
    v += __int_as_float(t);
    return v;
}

__device__ __forceinline__ int wrow_map(int r) {
    // padded LDS row -> global weight row (zero-x rows: any valid row)
    int r2 = (r >= 512) ? r - 12 : r;
    if ((r >= 500 && r < 512) || r >= 1012) r2 = 0;
    return r2;
}

extern "C" __global__ void __launch_bounds__(NTHR)
rnn_step(const int* __restrict__ X, const float* __restrict__ embed,
         const float* __restrict__ k1, const float* __restrict__ b1g,
         const float* __restrict__ k2, const float* __restrict__ b2g,
         char* __restrict__ ws, int s)
{
    __shared__ float s_x[16384];     // [1024 padded-k][16 b]
    __shared__ float s_w[2][8192];   // dbuf [128 rows][64 cols, row-XOR swz]
    // partials alias s_w[0]: wave w's segment == its own rows 16w..16w+15

    float* h1b = (float*)(ws + OFF_H1);
    float* h2b = (float*)(ws + OFF_H2);

    const int bid = blockIdx.x;
    const int tid = threadIdx.x;
    const int rr_ = bid >> 3;
    const int slice = (bid & 7) * 8 + (rr_ >> 2);  // XCD-grouped duplicates
    const int btile = rr_ & 3;
    const int L = slice >> 5;
    const int ut = slice & 31;          // units ut*16..+15
    const int b0 = btile * 16;

    const bool active = L ? (s >= 1) : (s < Tn);
    if (!active) return;

    const int w = tid >> 6;             // wave
    const int l = tid & 63;
    const int ks = l & 3;               // K sublane
    const int cg = (l >> 2) & 7;        // 8-col group
    const int bg = l >> 5;              // 8-batch half

    const float* Wm = L ? k2 : k1;      // [1000][2000], col = g*500+u
    const float* bv = L ? b2g : b1g;
    double* cb = (double*)(ws + (L ? OFF_C2 : OFF_C1));

    const int cur = s & 1, prv = cur ^ 1;
    const float* h1p = h1b + prv * 32000;
    const float* h2p = h2b + prv * 32000;
    float* houtT = (L ? h2b : h1b) + cur * 32000;
    const int t = L ? (s - 1) : s;
    const float* hlow = h1p;                    // first-half h source (L1)
    const float* hhigh = L ? h2p : h1p;         // second-half h source

    // ---- weight gll lane consts: dest row-in-inst wdr, dest col-quad wcq;
    //      stored (row, col') holds W[.][col' ^ ((row&3)<<3)] ----
    const int wdr = l >> 4;                     // 0..3
    const int wcq = l & 15;
    const int c_l = (4 * wcq) ^ (wdr << 3);     // logical col for this lane
    const int wcol = (c_l >> 4) * 500 + min(ut * 16 + (c_l & 15), 496);

    // ---- x gll lane consts ----
    const int xdr = l >> 2;                     // row 0..15 within piece
    const int xq4 = (l & 3) * 4;

    // ================= staging (manual pieces first, then glls) =========
    if (w == 7) {
        // piece c=3 rows 496..511: first 4 real, 500-511 zero
        if (L == 0) {
            const int eb = l & 15, r = 496 + (l >> 4);
            const float v = embed[(size_t)X[(b0 + eb) * Tn + t] * 500 + r];
            s_x[r * 16 + eb] = v;
        } else {
            if (l < 16) {
                const int r = 496 + (l >> 2);
                const float4 v = *(const float4*)(hlow + r * 64 + b0 + (l & 3) * 4);
                *(float4*)&s_x[r * 16 + (l & 3) * 4] = v;
            }
        }
        if (l < 48) {
            const int r = 500 + (l >> 2);
            *(float4*)&s_x[r * 16 + (l & 3) * 4] = make_float4(0.f, 0.f, 0.f, 0.f);
        }
        // piece c=7 rows 1008..1023: first 4 = h rows 496..499, rest zero
        if (l < 16) {
            const int r = 1008 + (l >> 2);
            const float4 v = *(const float4*)(hhigh + (r - 512) * 64 + b0 + (l & 3) * 4);
            *(float4*)&s_x[r * 16 + (l & 3) * 4] = v;
        }
        if (l < 48) {
            const int r = 1012 + (l >> 2);
            *(float4*)&s_x[r * 16 + (l & 3) * 4] = make_float4(0.f, 0.f, 0.f, 0.f);
        }
    }
    if (L == 0) {
        // embed-gather pieces (rows < 496), wave-local
        const int eb = l & 15, j = l >> 4;
        const int xid = X[(b0 + eb) * Tn + t];
        const float* er = embed + (size_t)xid * 500;
        #pragma unroll
        for (int c = 0; c < 4; ++c) {
            if (w < 7 || c < 3) {
                const int base = 128 * c + 16 * w;
                const float4 v = *(const float4*)(er + base + 4 * j);
                float* d = &s_x[(base + 4 * j) * 16 + eb];
                d[0] = v.x; d[16] = v.y; d[32] = v.z; d[48] = v.w;
            }
        }
        // h-part glls (rows 512..1007)
        #pragma unroll
        for (int c = 4; c < 8; ++c) {
            if (!(w == 7 && c == 7)) {
                const int base = 128 * c + 16 * w;
                const float* src = hhigh + (base - 512 + xdr) * 64 + b0 + xq4;
                __builtin_amdgcn_global_load_lds(src, &s_x[base * 16], 16, 0, 0);
            }
        }
    } else {
        #pragma unroll
        for (int c = 0; c < 8; ++c) {
            if (!(w == 7 && (c == 3 || c == 7))) {
                const int base = 128 * c + 16 * w;
                const float* src = (c < 4)
                    ? (hlow + (base + xdr) * 64 + b0 + xq4)
                    : (hhigh + (base - 512 + xdr) * 64 + b0 + xq4);
                __builtin_amdgcn_global_load_lds(src, &s_x[base * 16], 16, 0, 0);
            }
        }
    }
    // weight chunk 0 (wave-local rows)
    #pragma unroll
    for (int q = 0; q < 4; ++q) {
        const int lr = 16 * w + 4 * q;
        const int gr = wrow_map(lr + wdr);
        __builtin_amdgcn_global_load_lds(Wm + (size_t)gr * 2000 + wcol,
                                         &s_w[0][lr * 64], 16, 0, 0);
    }

    // ================= chunk loop: NO barriers, counted vmcnt ===========
    float4 acc[8][2];
    #pragma unroll
    for (int cc = 0; cc < 8; ++cc) {
        acc[cc][0] = make_float4(0.f, 0.f, 0.f, 0.f);
        acc[cc][1] = make_float4(0.f, 0.f, 0.f, 0.f);
    }

    #pragma unroll
    for (int c = 0; c < 8; ++c) {
        if (c < 7) {   // prefetch chunk c+1 into other buffer
            #pragma unroll
            for (int q = 0; q < 4; ++q) {
                const int lr = 16 * w + 4 * q;
                const int gr = wrow_map(128 * (c + 1) + lr + wdr);
                __builtin_amdgcn_global_load_lds(Wm + (size_t)gr * 2000 + wcol,
                                                 &s_w[(c + 1) & 1][lr * 64], 16, 0, 0);
            }
            asm volatile("s_waitcnt vmcnt(4)" ::: "memory");
        } else {
            asm volatile("s_waitcnt vmcnt(0)" ::: "memory");
        }
        __builtin_amdgcn_sched_barrier(0);
        const float* wb = s_w[c & 1];
        #pragma unroll
        for (int i = 0; i < 4; ++i) {
            const int lr = 16 * w + 4 * i + ks;             // row&3 == ks
            const float4 wA = *(const float4*)&wb[lr * 64 + ((cg ^ ks) << 3)];
            const float4 wB = *(const float4*)&wb[lr * 64 + ((cg ^ ks) << 3) + 4];
            const float* xr = &s_x[(128 * c + lr) * 16 + bg * 8];
            const float4 xA = *(const float4*)(xr);
            const float4 xB = *(const float4*)(xr + 4);
#define ACCUM(CC, WS) \
    acc[CC][0].x = fmaf(WS, xA.x, acc[CC][0].x); \
    acc[CC][0].y = fmaf(WS, xA.y, acc[CC][0].y); \
    acc[CC][0].z = fmaf(WS, xA.z, acc[CC][0].z); \
    acc[CC][0].w = fmaf(WS, xA.w, acc[CC][0].w); \
    acc[CC][1].x = fmaf(WS, xB.x, acc[CC][1].x); \
    acc[CC][1].y = fmaf(WS, xB.y, acc[CC][1].y); \
    acc[CC][1].z = fmaf(WS, xB.z, acc[CC][1].z); \
    acc[CC][1].w = fmaf(WS, xB.w, acc[CC][1].w);
            ACCUM(0, wA.x) ACCUM(1, wA.y) ACCUM(2, wA.z) ACCUM(3, wA.w)
            ACCUM(4, wB.x) ACCUM(5, wB.y) ACCUM(6, wB.z) ACCUM(7, wB.w)
#undef ACCUM
        }
    }

    // ---- ks-combine: DPP quad butterfly (f32), then ks==0 writes partials
    #pragma unroll
    for (int cc = 0; cc < 8; ++cc) {
        #pragma unroll
        for (int j = 0; j < 2; ++j) {
            acc[cc][j].x = qreduce(acc[cc][j].x);
            acc[cc][j].y = qreduce(acc[cc][j].y);
            acc[cc][j].z = qreduce(acc[cc][j].z);
            acc[cc][j].w = qreduce(acc[cc][j].w);
        }
    }
    if (ks == 0) {   // wave-local segment of s_w[0] (its own rows 16w..16w+15)
        float* p0 = &s_w[0][w * 1024];
        #pragma unroll
        for (int cc = 0; cc < 8; ++cc) {
            const int col = cg * 8 + cc;
            #pragma unroll
            for (int j = 0; j < 2; ++j) {
                const int pos = (bg * 8 + 4 * j) ^ (4 * (cg & 3));
                *(float4*)&p0[col * 16 + pos] = acc[cc][j];
            }
        }
    }
    __syncthreads();   // the ONLY barrier this step

    // ---- gates: f64 combine of 8 wave-partials + LSTM cell ----
    if (tid < 256) {
        const int gb = tid & 15;          // batch lane (2-way LDS banks)
        const int uu = tid >> 4;
        const int u = ut * 16 + uu;
        if (u < Hn) {
            double z[4];
            #pragma unroll
            for (int g = 0; g < 4; ++g) {
                const int col = g * 16 + uu;
                const int pos = gb ^ (4 * ((col >> 3) & 3));
                double zz = 0.0;
                #pragma unroll
                for (int q = 0; q < 8; ++q)
                    zz += (double)s_w[0][q * 1024 + col * 16 + pos];
                z[g] = zz + (double)bv[g * 500 + u];
            }
            const double gi = 1.0 / (1.0 + exp(-z[0]));
            const double gf = 1.0 / (1.0 + exp(-(z[2] + 1.0)));
            const double go_ = 1.0 / (1.0 + exp(-z[3]));
            const int ci = u * 64 + b0 + gb;
            const double cnew = gf * cb[ci] + gi * tanh(z[1]);
            cb[ci] = cnew;
            houtT[ci] = (float)(go_ * tanh(cnew));
        }
    }
}

// ---------- dense head (f64 accumulation), validated since round 1 ----------
extern "C" __global__ void __launch_bounds__(256)
head1(const char* __restrict__ ws_c, const float* __restrict__ w1,
      const float* __restrict__ bw1, char* __restrict__ ws)
{
    const float* lastT = (const float*)(ws_c + OFF_H2);  // h2 phase 0 (t=399)
    float* d1p = (float*)(ws + OFF_D1);
    const int o = blockIdx.x * 256 + threadIdx.x;        // 200 blocks
    if (o >= 51200) return;
    const int b = o / 800, j = o - b * 800;
    double acc = 0;
    for (int kk = 0; kk < 500; ++kk)
        acc += (double)lastT[kk * 64 + b] * (double)w1[(size_t)kk * 800 + j];
    acc += (double)bw1[j];
    d1p[b * 800 + j] = (float)fmax(acc, 0.0);
}

extern "C" __global__ void __launch_bounds__(256)
head2(const char* __restrict__ ws_c, const float* __restrict__ w2,
      const float* __restrict__ bw2, char* __restrict__ ws)
{
    const float* d1p = (const float*)(ws_c + OFF_D1);
    float* d2p = (float*)(ws + OFF_D2);
    const int o = blockIdx.x * 256 + threadIdx.x;        // 25 blocks
    if (o >= 6400) return;
    const int b = o / 100, j = o - b * 100;
    const float* dr = d1p + b * 800;
    double acc = 0;
    for (int kk = 0; kk < 800; ++kk)
        acc += (double)dr[kk] * (double)w2[(size_t)kk * 100 + j];
    acc += (double)bw2[j];
    d2p[b * 100 + j] = (float)fmax(acc, 0.0);
}

extern "C" __global__ void __launch_bounds__(128)
head3(const char* __restrict__ ws_c, const float* __restrict__ wpm,
      const float* __restrict__ bpv, float* __restrict__ out)
{
    const float* d2p = (const float*)(ws_c + OFF_D2);
    const int tid = threadIdx.x;                         // 1 block, 128 thr
    const int b = tid >> 1, cc = tid & 1;
    const float* dr = d2p + b * 100;
    double acc = 0;
    for (int kk = 0; kk < 100; ++kk)
        acc += (double)dr[kk] * (double)wpm[kk * 2 + cc];
    acc += (double)bpv[cc];
    out[b * 2 + cc] = (float)acc;
}

extern "C" void kernel_launch(void* const* d_in, const int* in_sizes, int n_in,
                              void* d_out, int out_size, void* d_ws, size_t ws_size,
                              hipStream_t stream) {
    const int* X = (const int*)d_in[0];
    const float* embed = (const float*)d_in[1];
    const float* k1 = (const float*)d_in[2];
    const float* b1 = (const float*)d_in[3];
    const float* k2 = (const float*)d_in[4];
    const float* b2 = (const float*)d_in[5];
    const float* w1 = (const float*)d_in[6];
    const float* bw1 = (const float*)d_in[7];
    const float* w2 = (const float*)d_in[8];
    const float* bw2 = (const float*)d_in[9];
    const float* wpm = (const float*)d_in[10];
    const float* bpv = (const float*)d_in[11];
    char* ws = (char*)d_ws;

    // zero h (both phases) + c (f64) — captured: clean state every replay
    hipMemsetAsync(d_ws, 0, WS_ZERO, stream);

    for (int s = 0; s <= Tn; ++s)
        rnn_step<<<256, NTHR, 0, stream>>>(X, embed, k1, b1, k2, b2, ws, s);

    head1<<<200, 256, 0, stream>>>(ws, w1, bw1, ws);
    head2<<<25, 256, 0, stream>>>(ws, w2, bw2, ws);
    head3<<<1, 128, 0, stream>>>(ws, wpm, bpv, (float*)d_out);
}